// Round 15
// baseline (1907.302 us; speedup 1.0000x reference)
//
#include <hip/hip_runtime.h>

// LinearShift: out = round_to_fixed(x) @ v.T + round_to_fixed(bias)
// f16 MFMA GEMM, fp32 accum: absmax 0.0 validated (rounds 7, 10, 11, 13).
// ROUND 15 (r14 bf16-32x32 NaN -> reverted): BK 64->32 halves LDS to 64KB
// -> 2 blocks/CU (16 waves) for cross-block TLP (m114). Swizzle re-derived
// for 64B rows: key (fr>>1)&3. STAGE = 1 load -> gates become vmcnt(2),
// same ledger proof shape as r10. 8 MFMA/phase. launch_bounds(512,4).

typedef _Float16 half8 __attribute__((ext_vector_type(8)));
typedef _Float16 half4v __attribute__((ext_vector_type(4)));
typedef float floatx4 __attribute__((ext_vector_type(4)));

__device__ __forceinline__ float qfix(float x) {
    float r = floorf(x * 256.0f + 0.5f);
    r = fminf(fmaxf(r, -32768.0f), 32767.0f);
    return r * 0.00390625f;
}

__global__ __launch_bounds__(256) void quantize_x_kernel(
        const float* __restrict__ x, _Float16* __restrict__ xq, int n4) {
    int i = blockIdx.x * 256 + threadIdx.x;
    const int stride = gridDim.x * 256;
    for (; i < n4; i += stride) {
        float4 v = reinterpret_cast<const float4*>(x)[i];
        half4v o;
        o[0] = (_Float16)qfix(v.x);
        o[1] = (_Float16)qfix(v.y);
        o[2] = (_Float16)qfix(v.z);
        o[3] = (_Float16)qfix(v.w);
        reinterpret_cast<half4v*>(xq)[i] = o;
    }
}

__global__ __launch_bounds__(256) void make_v_kernel(
        const float* __restrict__ shift, const float* __restrict__ sign,
        _Float16* __restrict__ v, int n4) {
    int i = blockIdx.x * 256 + threadIdx.x;
    const int stride = gridDim.x * 256;
    for (; i < n4; i += stride) {
        float4 sh = reinterpret_cast<const float4*>(shift)[i];
        float4 sg = reinterpret_cast<const float4*>(sign)[i];
        half4v o;
        o[0] = (_Float16)ldexpf((rintf(sg.x) == 0.0f) ? 1.0f : -1.0f, (int)rintf(sh.x));
        o[1] = (_Float16)ldexpf((rintf(sg.y) == 0.0f) ? 1.0f : -1.0f, (int)rintf(sh.y));
        o[2] = (_Float16)ldexpf((rintf(sg.z) == 0.0f) ? 1.0f : -1.0f, (int)rintf(sh.z));
        o[3] = (_Float16)ldexpf((rintf(sg.w) == 0.0f) ? 1.0f : -1.0f, (int)rintf(sh.w));
        reinterpret_cast<half4v*>(v)[i] = o;
    }
}

__device__ __forceinline__ void async_load16(const void* g, void* l) {
    __builtin_amdgcn_global_load_lds(
        (const __attribute__((address_space(1))) unsigned int*)g,
        (__attribute__((address_space(3))) unsigned int*)l,
        16, 0, 0);
}

// Stage one half-tile (128 rows x 32 f16 = 8KB): 1 load/thread.
// Thread t covers row r0=t>>2, block t&3; source col block pre-XOR'd:
// LDS[r][b] = G[row0+r][k0 + (b ^ ((r>>1)&3))*8]. Dest linear (t*16B).
#define STAGE(P, DST) async_load16((P), (DST) + t * 8)

// 16x16x32 frag (validated): row = fr (lane&15), k-block kb = lane>>4.
// Read undoes the swizzle: byte = row*64 + ((kb ^ ((fr>>1)&3))<<4) = row*64+xk.
#define READ_AF(QM)                                                       \
    _Pragma("unroll")                                                     \
    for (int mf = 0; mf < 4; ++mf)                                        \
      af[mf] = *reinterpret_cast<const half8*>(                           \
          aRow + sb + (QM) * 8192 + mf * 1024);

#define READ_BF(QN)                                                       \
    _Pragma("unroll")                                                     \
    for (int nf = 0; nf < 2; ++nf)                                        \
      bf[nf] = *reinterpret_cast<const half8*>(                           \
          (nf ? bR1 : bR0) + sb + (QN) * 8192);

#define MFMA_QUAD(ACCQ)                                                   \
    _Pragma("unroll")                                                     \
    for (int mf = 0; mf < 4; ++mf)                                        \
      _Pragma("unroll")                                                   \
      for (int nf = 0; nf < 2; ++nf)                                      \
        ACCQ[mf][nf] = __builtin_amdgcn_mfma_f32_16x16x32_f16(            \
            af[mf], bf[nf], ACCQ[mf][nf], 0, 0, 0);

#define PHASE_CORE(ACCQ)                                                  \
    asm volatile("" ::: "memory");                                        \
    __builtin_amdgcn_s_barrier();                                         \
    __builtin_amdgcn_s_setprio(1);                                        \
    MFMA_QUAD(ACCQ);                                                      \
    __builtin_amdgcn_s_setprio(0);

#define END_BARRIER()                                                     \
    asm volatile("" ::: "memory");                                        \
    __builtin_amdgcn_s_barrier();

#define VM2()  asm volatile("s_waitcnt vmcnt(2)" ::: "memory")
#define VM0()  asm volatile("s_waitcnt vmcnt(0)" ::: "memory")

// LDS (dynamic, 64KB): [slot(2)][A0,A1,B0,B1][128][32] f16, 4096 f16/half.
// Slot stride 32768B; halves: A0@0, A1@8192B, B0@16384B, B1@24576B.
__global__ __launch_bounds__(512, 4) void gemm8_kernel(
        const _Float16* __restrict__ A,   // M x K
        const _Float16* __restrict__ B,   // N x K
        const float* __restrict__ bias,   // N
        float* __restrict__ C,            // M x N
        int M, int N, int K) {
    extern __shared__ _Float16 smem[];
    const int t = threadIdx.x;
    const int lane = t & 63;
    const int w = t >> 6;
    const int wrow = w >> 2;   // 0..1
    const int wcol = w & 3;    // 0..3
    const int fr  = lane & 15;
    const int kb  = lane >> 4; // 0..3

    // T1: bijective XCD swizzle (nwg % 8 == 0 for this shape)
    const int nwg = gridDim.x;
    const int bid = blockIdx.x;
    const int cpx = nwg >> 3;
    const int swz = (bid & 7) * cpx + (bid >> 3);
    const int ntN = N >> 8;
    const int bm = (swz / ntN) << 8;
    const int bn = (swz % ntN) << 8;

    // Running global stage pointers (+32 els/tile).
    const int r0  = t >> 2;
    const int cbo = ((t & 3) ^ ((t >> 3) & 3)) * 8;
    const _Float16* pA0 = A + (size_t)(bm +       r0) * K + cbo;
    const _Float16* pA1 = A + (size_t)(bm + 128 + r0) * K + cbo;
    const _Float16* pB0 = B + (size_t)(bn +       r0) * K + cbo;
    const _Float16* pB1 = B + (size_t)(bn + 128 + r0) * K + cbo;

    // Precomputed swizzled LDS read bases (bytes, slot 0).
    const int xk = ((kb ^ ((fr >> 1) & 3)) << 4);
    const char* sbase = (const char*)smem;
    const char* aRow = sbase + (wrow * 64 + fr) * 64 + xk;           // + QM*8192 + mf*1024
    const char* bR0  = sbase + 16384 + (wcol * 32 +      fr) * 64 + xk;  // + QN*8192
    const char* bR1  = sbase + 16384 + (wcol * 32 + 16 + fr) * 64 + xk;

    // prologue: stage K-tile 0 into slot 0, drain once; advance pointers
    STAGE(pA0, smem);            // A0
    STAGE(pB0, smem + 8192);     // B0 (8192 els = 16384 B)
    STAGE(pB1, smem + 12288);    // B1 (24576 B)
    STAGE(pA1, smem + 4096);     // A1 (8192 B)
    VM0();
    __builtin_amdgcn_s_barrier();
    pA0 += 32; pA1 += 32; pB0 += 32; pB1 += 32;

    floatx4 acc[2][2][4][2] = {};   // [qm][qn][mf][nf] — all static-indexed
    const int NT = K >> 5;          // 128

    // Ledger (1-load STAGEs): entering tile kt>=1, {B1,A1}@cur = 2 outstanding.
    // P1 stages A0'(+1=3) -> VM2 retires B1@cur; P2 stages B0'(+1=3) -> VM2
    // retires A1@cur; P3 stages B1'(+1=3); P4 stages A1'(+1=4) -> VM2 retires
    // {A0',B0'}. kt=0: prologue drained, gates are safe no-ops. Last tile
    // stages nothing: P1 drains VM0; P2/P4 skip gates.
    for (int kt = 0; kt < NT; ++kt) {
        const int sb = (kt & 1) << 15;                        // read-slot bytes
        _Float16* nslot = smem + (((kt & 1) ^ 1) << 14);      // staging slot (els)
        const bool more = (kt + 1 < NT);

        half8 af[4], bf[2];

        // Phase 1: (qm0, qn0)
        READ_AF(0);
        READ_BF(0);
        if (more) STAGE(pA0, nslot);
        PHASE_CORE(acc[0][0]);
        if (more) { VM2(); } else { VM0(); }
        END_BARRIER();

        // Phase 2: (qm0, qn1)
        READ_BF(1);
        if (more) STAGE(pB0, nslot + 8192);
        PHASE_CORE(acc[0][1]);
        if (more) { VM2(); }
        END_BARRIER();

        // Phase 3: (qm1, qn1)
        READ_AF(1);
        if (more) STAGE(pB1, nslot + 12288);
        PHASE_CORE(acc[1][1]);
        END_BARRIER();

        // Phase 4: (qm1, qn0) — re-read B qn0
        READ_BF(0);
        if (more) STAGE(pA1, nslot + 4096);
        PHASE_CORE(acc[1][0]);
        if (more) { VM2(); }
        END_BARRIER();

        if (more) { pA0 += 32; pA1 += 32; pB0 += 32; pB1 += 32; }
    }

    // Epilogue: C/D layout col=lane&15, row=(lane>>4)*4+reg (validated)
    #pragma unroll
    for (int qm = 0; qm < 2; ++qm)
      #pragma unroll
      for (int qn = 0; qn < 2; ++qn)
        #pragma unroll
        for (int nf = 0; nf < 2; ++nf) {
            const int gcol = bn + qn * 128 + wcol * 32 + nf * 16 + (lane & 15);
            const float bq = qfix(bias[gcol]);
            #pragma unroll
            for (int mf = 0; mf < 4; ++mf) {
                const int grow = bm + qm * 128 + wrow * 64 + mf * 16 + ((lane >> 4) << 2);
                float* p = C + (size_t)grow * N + gcol;
                #pragma unroll
                for (int r = 0; r < 4; ++r)
                    p[(size_t)r * N] = acc[qm][qn][mf][nf][r] + bq;
            }
        }
}

extern "C" void kernel_launch(void* const* d_in, const int* in_sizes, int n_in,
                              void* d_out, int out_size, void* d_ws, size_t ws_size,
                              hipStream_t stream) {
    const float* x     = (const float*)d_in[0];
    const float* shift = (const float*)d_in[1];
    const float* sign  = (const float*)d_in[2];
    const float* bias  = (const float*)d_in[3];
    float* out = (float*)d_out;

    const int N = in_sizes[3];            // 4096
    const int K = in_sizes[1] / N;        // 4096
    const int M = in_sizes[0] / K;        // 8192

    _Float16* xq = (_Float16*)d_ws;
    _Float16* v  = (_Float16*)((char*)d_ws + (size_t)M * K * sizeof(_Float16));

    quantize_x_kernel<<<2048, 256, 0, stream>>>(x, xq, M * K / 4);
    make_v_kernel<<<2048, 256, 0, stream>>>(shift, sign, v, N * K / 4);

    (void)hipFuncSetAttribute(reinterpret_cast<const void*>(gemm8_kernel),
                              hipFuncAttributeMaxDynamicSharedMemorySize, 65536);
    const int nblk = (M / 256) * (N / 256);
    gemm8_kernel<<<nblk, 512, 65536, stream>>>(xq, v, bias, out, M, N, K);
}

// Round 16
// 306.309 us; speedup vs baseline: 6.2267x; 6.2267x over previous
//
#include <hip/hip_runtime.h>

// LinearShift: out = round_to_fixed(x) @ v.T + round_to_fixed(bias)
// f16 MFMA GEMM, fp32 accum: absmax 0.0 validated (r7, r10, r11, r13, r15).
// ROUND 16: deep-lookahead single-region schedule. BK=32, 4 LDS slots
// (128KB), lookahead 3 K-tiles. Per K-tile: ONE barrier, 12 independent
// ds_read_b128, 4 stage-issues (tile t+3), 32 MFMA, ONE vmcnt(8) gate.
// (r15 post-mortem: 256^2@512thr is pinned at 1 block/CU -- acc alone is
// 128 VGPR; launch_bounds(512,2). r15's BK=32 addressing reused verbatim.)

typedef _Float16 half8 __attribute__((ext_vector_type(8)));
typedef _Float16 half4v __attribute__((ext_vector_type(4)));
typedef float floatx4 __attribute__((ext_vector_type(4)));

__device__ __forceinline__ float qfix(float x) {
    float r = floorf(x * 256.0f + 0.5f);
    r = fminf(fmaxf(r, -32768.0f), 32767.0f);
    return r * 0.00390625f;
}

__global__ __launch_bounds__(256) void quantize_x_kernel(
        const float* __restrict__ x, _Float16* __restrict__ xq, int n4) {
    int i = blockIdx.x * 256 + threadIdx.x;
    const int stride = gridDim.x * 256;
    for (; i < n4; i += stride) {
        float4 v = reinterpret_cast<const float4*>(x)[i];
        half4v o;
        o[0] = (_Float16)qfix(v.x);
        o[1] = (_Float16)qfix(v.y);
        o[2] = (_Float16)qfix(v.z);
        o[3] = (_Float16)qfix(v.w);
        reinterpret_cast<half4v*>(xq)[i] = o;
    }
}

__global__ __launch_bounds__(256) void make_v_kernel(
        const float* __restrict__ shift, const float* __restrict__ sign,
        _Float16* __restrict__ v, int n4) {
    int i = blockIdx.x * 256 + threadIdx.x;
    const int stride = gridDim.x * 256;
    for (; i < n4; i += stride) {
        float4 sh = reinterpret_cast<const float4*>(shift)[i];
        float4 sg = reinterpret_cast<const float4*>(sign)[i];
        half4v o;
        o[0] = (_Float16)ldexpf((rintf(sg.x) == 0.0f) ? 1.0f : -1.0f, (int)rintf(sh.x));
        o[1] = (_Float16)ldexpf((rintf(sg.y) == 0.0f) ? 1.0f : -1.0f, (int)rintf(sh.y));
        o[2] = (_Float16)ldexpf((rintf(sg.z) == 0.0f) ? 1.0f : -1.0f, (int)rintf(sh.z));
        o[3] = (_Float16)ldexpf((rintf(sg.w) == 0.0f) ? 1.0f : -1.0f, (int)rintf(sh.w));
        reinterpret_cast<half4v*>(v)[i] = o;
    }
}

__device__ __forceinline__ void async_load16(const void* g, void* l) {
    __builtin_amdgcn_global_lo\
ad_lds(
        (const __attribute__((address_space(1))) unsigned int*)g,
        (__attribute__((address_space(3))) unsigned int*)l,
        16, 0, 0);
}

// Stage one half-tile (128 rows x 32 f16 = 8KB): 1 load/thread (r15-validated).
// LDS[r][b] = G[row0+r][k0 + (b ^ ((r>>1)&3))*8], r = t>>2, b = t&3.
#define STAGE(P, DST) async_load16((P), (DST) + t * 8)

// Stage all 4 halves of one K-tile into slot base NS (elements):
// A0@0, A1@4096, B0@8192, B1@12288.
#define STAGE_TILE(NS)  do {                                              \
    STAGE(pA0, (NS));            STAGE(pB0, (NS) + 8192);                 \
    STAGE(pB1, (NS) + 12288);    STAGE(pA1, (NS) + 4096);                 \
    pA0 += 32; pA1 += 32; pB0 += 32; pB1 += 32; } while (0)

#define VM8()  asm volatile("s_waitcnt vmcnt(8)" ::: "memory")
#define VM4()  asm volatile("s_waitcnt vmcnt(4)" ::: "memory")
#define VM0()  asm volatile("s_waitcnt vmcnt(0)" ::: "memory")
#define BAR()  do { asm volatile("" ::: "memory");                        \
                    __builtin_amdgcn_s_barrier();                         \
                    asm volatile("" ::: "memory"); } while (0)

// LDS (dynamic, 128KB): 4 slots x [A0,A1,B0,B1][128][32] f16 (32KB/slot).
__global__ __launch_bounds__(512, 2) void gemm8_kernel(
        const _Float16* __restrict__ A,   // M x K
        const _Float16* __restrict__ B,   // N x K
        const float* __restrict__ bias,   // N
        float* __restrict__ C,            // M x N
        int M, int N, int K) {
    extern __shared__ _Float16 smem[];
    const int t = threadIdx.x;
    const int lane = t & 63;
    const int w = t >> 6;
    const int wrow = w >> 2;   // 0..1
    const int wcol = w & 3;    // 0..3
    const int fr  = lane & 15;
    const int kb  = lane >> 4; // 0..3

    // T1: bijective XCD swizzle (nwg % 8 == 0 for this shape)
    const int nwg = gridDim.x;
    const int bid = blockIdx.x;
    const int cpx = nwg >> 3;
    const int swz = (bid & 7) * cpx + (bid >> 3);
    const int ntN = N >> 8;
    const int bm = (swz / ntN) << 8;
    const int bn = (swz % ntN) << 8;

    // Running global stage pointers (+32 els/tile), r15-validated.
    const int r0  = t >> 2;
    const int cbo = ((t & 3) ^ ((t >> 3) & 3)) * 8;
    const _Float16* pA0 = A + (size_t)(bm +       r0) * K + cbo;
    const _Float16* pA1 = A + (size_t)(bm + 128 + r0) * K + cbo;
    const _Float16* pB0 = B + (size_t)(bn +       r0) * K + cbo;
    const _Float16* pB1 = B + (size_t)(bn + 128 + r0) * K + cbo;

    // Precomputed swizzled LDS read bases (bytes, slot 0), r15-validated:
    // read byte = row*64 + ((kb ^ ((row>>1)&3))<<4).
    const int xk = ((kb ^ ((fr >> 1) & 3)) << 4);
    const char* sbase = (const char*)smem;
    const char* aRow = sbase + (wrow * 64 + fr) * 64 + xk;               // +qm*8192 +mf*1024
    const char* bR0  = sbase + 16384 + (wcol * 32 +      fr) * 64 + xk;  // +qn*8192
    const char* bR1  = sbase + 16384 + (wcol * 32 + 16 + fr) * 64 + xk;

    // Prologue: stage tiles 0,1,2 into slots 0,1,2 (12 loads), then retire
    // tile 0 (vmcnt(8): 12 outstanding -> 8 leaves tiles 1,2).
    STAGE_TILE(smem);
    STAGE_TILE(smem + 16384);
    STAGE_TILE(smem + 32768);
    VM8();

    floatx4 acc[2][2][4][2] = {};   // [qm][qn][mf][nf] — all static-indexed
    const int NT = K >> 5;          // 128

    // Per-tile ledger: entering tile T (after prev gate + barrier), slot T&3
    // fully resident. Body stages tile T+3 into slot (T+3)&3 (= slot of tile
    // T-1, whose reads completed before this barrier -- WAR safe). End gate:
    //   T < NT-3 : vmcnt(8)  (outstanding {T+1,T+2,T+3}<=12 -> retires T+1)
    //   T == NT-3: vmcnt(4)  (outstanding {T+1,T+2}        -> retires T+1)
    //   T == NT-2: vmcnt(0)  (outstanding {T+1}            -> retires T+1)
    //   T == NT-1: none.
    for (int T = 0; T < NT; ++T) {
        BAR();
        const int sb = (T & 3) << 15;   // read-slot byte offset

        // 12 independent ds_read_b128 (no B re-read: bf0/bf1 both live).
        half8 af0[4], af1[4], bf0[2], bf1[2];
        #pragma unroll
        for (int mf = 0; mf < 4; ++mf) {
            af0[mf] = *reinterpret_cast<const half8*>(aRow + sb +        mf * 1024);
            af1[mf] = *reinterpret_cast<const half8*>(aRow + sb + 8192 + mf * 1024);
        }
        bf0[0] = *reinterpret_cast<const half8*>(bR0 + sb);
        bf0[1] = *reinterpret_cast<const half8*>(bR1 + sb);
        bf1[0] = *reinterpret_cast<const half8*>(bR0 + sb + 8192);
        bf1[1] = *reinterpret_cast<const half8*>(bR1 + sb + 8192);

        // Stage tile T+3 (issue early; lands ~3 tiles from now).
        if (T < NT - 3)
            STAGE_TILE(smem + (((T + 3) & 3) << 14));

        // 32 MFMA, one scheduling region (no setprio: fences hurt, r12).
        #pragma unroll
        for (int mf = 0; mf < 4; ++mf)
          #pragma unroll
          for (int nf = 0; nf < 2; ++nf) {
            acc[0][0][mf][nf] = __builtin_amdgcn_mfma_f32_16x16x32_f16(
                af0[mf], bf0[nf], acc[0][0][mf][nf], 0, 0, 0);
            acc[0][1][mf][nf] = __builtin_amdgcn_mfma_f32_16x16x32_f16(
                af0[mf], bf1[nf], acc[0][1][mf][nf], 0, 0, 0);
            acc[1][1][mf][nf] = __builtin_amdgcn_mfma_f32_16x16x32_f16(
                af1[mf], bf1[nf], acc[1][1][mf][nf], 0, 0, 0);
            acc[1][0][mf][nf] = __builtin_amdgcn_mfma_f32_16x16x32_f16(
                af1[mf], bf0[nf], acc[1][0][mf][nf], 0, 0, 0);
          }

        if (T < NT - 3)      { VM8(); }
        else if (T == NT - 3){ VM4(); }
        else if (T == NT - 2){ VM0(); }
    }

    // Epilogue: C/D layout col=lane&15, row=(lane>>4)*4+reg (validated)
    #pragma unroll
    for (int qm = 0; qm < 2; ++qm)
      #pragma unroll
      for (int qn = 0; qn < 2; ++qn)
        #pragma unroll
        for (int nf = 0; nf < 2; ++nf) {
            const int gcol = bn + qn * 128 + wcol * 32 + nf * 16 + (lane & 15);
            const float bq = qfix(bias[gcol]);
            #pragma unroll
            for (int mf = 0; mf < 4; ++mf) {
                const int grow = bm + qm * 128 + wrow * 64 + mf * 16 + ((lane >> 4) << 2);
                float* p = C + (size_t)grow * N + gcol;
                #pragma unroll
                for (int r = 0; r < 4; ++r)
                    p[(size_t)r * N] = acc[qm][qn][mf][nf][r] + bq;
            }
        }
}

extern "C" void kernel_launch(void* const* d_in, const int* in_sizes, int n_in,
                              void* d_out, int out_size, void* d_ws, size_t ws_size,
                              hipStream_t stream) {
    const float* x     = (const float*)d_in[0];
    const float* shift = (const float*)d_in[1];
    const float* sign  = (const float*)d_in[2];
    const float* bias  = (const float*)d_in[3];
    float* out = (float*)d_out;

    const int N = in_sizes[3];            // 4096
    const int K = in_sizes[1] / N;        // 4096
    const int M = in_sizes[0] / K;        // 8192

    _Float16* xq = (_Float16*)d_ws;
    _Float16* v  = (_Float16*)((char*)d_ws + (size_t)M * K * sizeof(_Float16));

    quantize_x_kernel<<<2048, 256, 0, stream>>>(x, xq, M * K / 4);
    make_v_kernel<<<2048, 256, 0, stream>>>(shift, sign, v, N * K / 4);

    (void)hipFuncSetAttribute(reinterpret_cast<const void*>(gemm8_kernel),
                              hipFuncAttributeMaxDynamicSharedMemorySize, 131072);
    const int nblk = (M / 256) * (N / 256);
    gemm8_kernel<<<nblk, 512, 131072, stream>>>(xq, v, bias, out, M, N, K);
}